// Round 1
// baseline (71.189 us; speedup 1.0000x reference)
//
#include <hip/hip_runtime.h>

// ClusterLoss: loss = 0.5 * sum_{b,d} (X[b,d] - C[id[b],d])^2
// B=65536, D=1024, K=256. Memory-bound: one streaming pass over X (256 MiB).

#define D_DIM 1024
#define BLOCK 256   // thread t covers float4 at column t*4 -> exactly one row per block-iteration

__global__ __launch_bounds__(BLOCK) void cluster_loss_kernel(
    const float* __restrict__ X,
    const int*   __restrict__ ids,
    const float* __restrict__ C,
    float*       __restrict__ out,
    int B)
{
    const int t = threadIdx.x;
    float acc = 0.0f;

    for (int row = blockIdx.x; row < B; row += gridDim.x) {
        const int id = ids[row];  // same address across the block -> broadcast
        const float4 x = *reinterpret_cast<const float4*>(X + (size_t)row * D_DIM + t * 4);
        const float4 c = *reinterpret_cast<const float4*>(C + (size_t)id  * D_DIM + t * 4);
        const float dx = x.x - c.x;
        const float dy = x.y - c.y;
        const float dz = x.z - c.z;
        const float dw = x.w - c.w;
        acc = fmaf(dx, dx, acc);
        acc = fmaf(dy, dy, acc);
        acc = fmaf(dz, dz, acc);
        acc = fmaf(dw, dw, acc);
    }

    // wave-64 butterfly reduce
    #pragma unroll
    for (int off = 32; off > 0; off >>= 1)
        acc += __shfl_down(acc, off, 64);

    __shared__ float wave_sum[BLOCK / 64];
    if ((t & 63) == 0) wave_sum[t >> 6] = acc;
    __syncthreads();

    if (t == 0) {
        float s = wave_sum[0] + wave_sum[1] + wave_sum[2] + wave_sum[3];
        atomicAdd(out, 0.5f * s);
    }
}

extern "C" void kernel_launch(void* const* d_in, const int* in_sizes, int n_in,
                              void* d_out, int out_size, void* d_ws, size_t ws_size,
                              hipStream_t stream)
{
    const float* X   = (const float*)d_in[0];
    const int*   ids = (const int*)  d_in[1];
    const float* C   = (const float*)d_in[2];
    float*       out = (float*)d_out;

    const int B = in_sizes[1];  // 65536 rows (in_sizes[0] = B*D)

    // d_out is poisoned (0xAA) before timing and not re-zeroed between replays.
    hipMemsetAsync(out, 0, sizeof(float), stream);

    const int grid = 2048;  // 8 blocks/CU, grid-stride over 65536 rows
    cluster_loss_kernel<<<grid, BLOCK, 0, stream>>>(X, ids, C, out, B);
}

// Round 2
// 60.394 us; speedup vs baseline: 1.1787x; 1.1787x over previous
//
#include <hip/hip_runtime.h>

// ClusterLoss: loss = 0.5 * sum_{b,d} (X[b,d] - C[id[b],d])^2
// B=65536, D=1024, K=256.
// Memory-bound: one streaming pass over X (256 MiB); C (1 MiB) is L2-resident.
// X is loaded nontemporally so the stream doesn't evict the C table from L2.

typedef float f4 __attribute__((ext_vector_type(4)));

#define D_DIM 1024
#define BLOCK 256          // thread t covers float4 at column t*4 -> one row per row-step
#define ROWS_PER_BLOCK 32  // 65536 / 2048 blocks
#define UNROLL 4           // rows in flight per iteration (MLP for the id->C chain)

__global__ __launch_bounds__(BLOCK) void cluster_loss_kernel(
    const float* __restrict__ X,
    const int*   __restrict__ ids,
    const float* __restrict__ C,
    float*       __restrict__ out,
    int B)
{
    const int t = threadIdx.x;
    const int row0 = blockIdx.x * ROWS_PER_BLOCK;
    float acc = 0.0f;

    if (row0 + ROWS_PER_BLOCK <= B) {
        const float* xb = X + (size_t)row0 * D_DIM + t * 4;
        #pragma unroll 2
        for (int i = 0; i < ROWS_PER_BLOCK; i += UNROLL) {
            int id[UNROLL];
            f4  x[UNROLL];
            #pragma unroll
            for (int u = 0; u < UNROLL; ++u) {
                id[u] = ids[row0 + i + u];                       // block-uniform -> scalar load
                x[u]  = __builtin_nontemporal_load(
                          reinterpret_cast<const f4*>(xb + (size_t)(i + u) * D_DIM));
            }
            #pragma unroll
            for (int u = 0; u < UNROLL; ++u) {
                const f4 c = *reinterpret_cast<const f4*>(C + (size_t)id[u] * D_DIM + t * 4);
                const f4 d = x[u] - c;
                acc = fmaf(d.x, d.x, acc);
                acc = fmaf(d.y, d.y, acc);
                acc = fmaf(d.z, d.z, acc);
                acc = fmaf(d.w, d.w, acc);
            }
        }
    } else {
        // generic tail (not hit for B=65536 with grid = B/ROWS_PER_BLOCK)
        for (int row = row0; row < B; ++row) {
            const int id = ids[row];
            const f4 x = __builtin_nontemporal_load(
                           reinterpret_cast<const f4*>(X + (size_t)row * D_DIM + t * 4));
            const f4 c = *reinterpret_cast<const f4*>(C + (size_t)id * D_DIM + t * 4);
            const f4 d = x - c;
            acc = fmaf(d.x, d.x, acc);
            acc = fmaf(d.y, d.y, acc);
            acc = fmaf(d.z, d.z, acc);
            acc = fmaf(d.w, d.w, acc);
        }
    }

    // wave-64 butterfly reduce
    #pragma unroll
    for (int off = 32; off > 0; off >>= 1)
        acc += __shfl_down(acc, off, 64);

    __shared__ float wave_sum[BLOCK / 64];
    if ((t & 63) == 0) wave_sum[t >> 6] = acc;
    __syncthreads();

    if (t == 0) {
        float s = wave_sum[0] + wave_sum[1] + wave_sum[2] + wave_sum[3];
        atomicAdd(out, 0.5f * s);
    }
}

extern "C" void kernel_launch(void* const* d_in, const int* in_sizes, int n_in,
                              void* d_out, int out_size, void* d_ws, size_t ws_size,
                              hipStream_t stream)
{
    const float* X   = (const float*)d_in[0];
    const int*   ids = (const int*)  d_in[1];
    const float* C   = (const float*)d_in[2];
    float*       out = (float*)d_out;

    const int B = in_sizes[1];  // 65536 rows

    // d_out is poisoned (0xAA) before timing and not re-zeroed between replays.
    hipMemsetAsync(out, 0, sizeof(float), stream);

    const int grid = (B + ROWS_PER_BLOCK - 1) / ROWS_PER_BLOCK;  // 2048
    cluster_loss_kernel<<<grid, BLOCK, 0, stream>>>(X, ids, C, out, B);
}